// Round 14
// baseline (456.491 us; speedup 1.0000x reference)
//
#include <hip/hip_runtime.h>
#include <hip/hip_bf16.h>
#include <math.h>

#define Bb 2
#define Ss 2048
#define Cc 1536
#define HQ 8
#define DQK 128
#define DV 192
#define ROWS (Bb*Ss)          // 4096
#define NQKV 1408             // 1024 q + 128 k + 192 v + 64 pad (11*128)
#define EPSf 1e-5f
#define CLIPf 5.0f

typedef short short8 __attribute__((ext_vector_type(8)));
typedef float f32x4 __attribute__((ext_vector_type(4)));
typedef unsigned short ushort;
typedef ushort us4 __attribute__((ext_vector_type(4)));

// ---------------- helpers ----------------
__device__ __forceinline__ float wave_sum(float v) {
#pragma unroll
    for (int off = 32; off >= 1; off >>= 1) v += __shfl_xor(v, off);
    return v;
}

__device__ __forceinline__ ushort bf16_bits(float f) {
    __hip_bfloat16 hb = __float2bfloat16(f);
    return *reinterpret_cast<ushort*>(&hb);
}

__device__ __forceinline__ float bfu(ushort u) {
    unsigned v = (unsigned)u << 16;
    return *reinterpret_cast<float*>(&v);
}

__device__ __forceinline__ void gld16(const void* g, void* l) {
    __builtin_amdgcn_global_load_lds(
        (const __attribute__((address_space(1))) void*)g,
        (__attribute__((address_space(3))) void*)l, 16, 0, 0);
}

// ---------------- rms_bn reduce (per-channel over B*S) ----------------
__global__ void sq_reduce(const float* __restrict__ x, float* __restrict__ ms, int ncols) {
    int ch = blockIdx.x * blockDim.x + threadIdx.x;
    int r0 = blockIdx.y * 128;
    float acc = 0.f;
    for (int r = r0; r < r0 + 128; ++r) {
        float v = x[(size_t)r * ncols + ch];
        acc += v * v;
    }
    atomicAdd(&ms[ch], acc);
}

// ---------------- rms apply, vectorized x4; BF16 template selects output ----------------
template <int BF16>
__global__ void rms_apply_v(const float* __restrict__ x, const float* __restrict__ ms,
                            const float* __restrict__ scale, void* __restrict__ outp,
                            int ncols4, size_t total4) {
    for (size_t i = (size_t)blockIdx.x * blockDim.x + threadIdx.x; i < total4;
         i += (size_t)gridDim.x * blockDim.x) {
        int c4 = (int)(i % ncols4);
        float4 v = ((const float4*)x)[i];
        float4 m4 = ((const float4*)ms)[c4];
        float4 s4 = ((const float4*)scale)[c4];
        float o0 = v.x * rsqrtf(m4.x * (1.0f / ROWS) + EPSf) * s4.x;
        float o1 = v.y * rsqrtf(m4.y * (1.0f / ROWS) + EPSf) * s4.y;
        float o2 = v.z * rsqrtf(m4.z * (1.0f / ROWS) + EPSf) * s4.z;
        float o3 = v.w * rsqrtf(m4.w * (1.0f / ROWS) + EPSf) * s4.w;
        if (BF16) {
            us4 o = {bf16_bits(o0), bf16_bits(o1), bf16_bits(o2), bf16_bits(o3)};
            ((us4*)outp)[i] = o;
        } else {
            float4 o = {o0, o1, o2, o3};
            ((float4*)outp)[i] = o;
        }
    }
}

// ---------------- fused fp32 -> bf16 weight conversion (4 segments) ----------------
__global__ void cvt_all(const float* __restrict__ q_w, const float* __restrict__ k_w,
                        const float* __restrict__ v_w, const float* __restrict__ ow,
                        ushort* __restrict__ qkvwh, ushort* __restrict__ owh) {
    const int QN = 1024 * Cc / 4, KN = 128 * Cc / 4, VN = 192 * Cc / 4, ON = Cc * Cc / 4;
    int i = blockIdx.x * 256 + threadIdx.x;
    const float* src;
    us4* dst;
    int off;
    if (i < QN)                  { src = q_w; dst = (us4*)qkvwh;                         off = i; }
    else if (i < QN + KN)        { src = k_w; dst = (us4*)(qkvwh + (size_t)1024 * Cc);   off = i - QN; }
    else if (i < QN + KN + VN)   { src = v_w; dst = (us4*)(qkvwh + (size_t)1152 * Cc);   off = i - QN - KN; }
    else if (i < QN + KN + VN + ON) { src = ow; dst = (us4*)owh;                         off = i - QN - KN - VN; }
    else return;
    float4 v = ((const float4*)src)[off];
    us4 o = {bf16_bits(v.x), bf16_bits(v.y), bf16_bits(v.z), bf16_bits(v.w)};
    dst[off] = o;
}

// ---------------- bf16 MFMA GEMM: C[M,N] = A[M,K] * W[N,K]^T (+bias) ----------------
// BM=BN=128, BK=32, 256 thr (2x2 waves, 64x64/wave, 4x4 frags of 16x16x32).
// OUTBF16 selects fp32 or bf16 output.
template <int OUTBF16>
__global__ __launch_bounds__(256) void gemm_bf16(const ushort* __restrict__ A,
                                                 const ushort* __restrict__ W,
                                                 const float* __restrict__ bias,
                                                 void* __restrict__ Cout,
                                                 int N, int K, int hasBias) {
    __shared__ ushort AS[4096];  // 8 KB
    __shared__ ushort WS[4096];  // 8 KB
    int tid = threadIdx.x;
    int w = tid >> 6, lane = tid & 63;
    int gl = lane >> 4, li = lane & 15;
    int wr = w >> 1, wc = w & 1;
    int m0 = blockIdx.y * 128, n0 = blockIdx.x * 128;

    int r = tid & 127, gg = tid >> 7;
    const ushort* pA = A + (size_t)(m0 + r) * K + gg * 8;
    const ushort* pW = W + (size_t)(n0 + r) * K + gg * 8;
    ushort* lA0 = &AS[w * 512];
    ushort* lA1 = &AS[2048 + w * 512];
    ushort* lW0 = &WS[w * 512];
    ushort* lW1 = &WS[2048 + w * 512];

    const ushort* fA = &AS[(gl * 128 + wr * 64 + li) * 8];
    const ushort* fW = &WS[(gl * 128 + wc * 64 + li) * 8];

    f32x4 acc[4][4];
#pragma unroll
    for (int m = 0; m < 4; ++m)
#pragma unroll
        for (int n = 0; n < 4; ++n) acc[m][n] = (f32x4){0.f, 0.f, 0.f, 0.f};

    for (int kk = 0; kk < K; kk += 32) {
        __syncthreads();
        gld16(pA + kk, lA0);
        gld16(pA + kk + 16, lA1);
        gld16(pW + kk, lW0);
        gld16(pW + kk + 16, lW1);
        __syncthreads();
        short8 a[4], b[4];
#pragma unroll
        for (int m = 0; m < 4; ++m) a[m] = *(const short8*)(fA + m * 128);
#pragma unroll
        for (int n = 0; n < 4; ++n) b[n] = *(const short8*)(fW + n * 128);
#pragma unroll
        for (int m = 0; m < 4; ++m)
#pragma unroll
            for (int n = 0; n < 4; ++n)
                acc[m][n] = __builtin_amdgcn_mfma_f32_16x16x32_bf16(a[m], b[n], acc[m][n], 0, 0, 0);
    }

#pragma unroll
    for (int m = 0; m < 4; ++m) {
        int row = m0 + wr * 64 + m * 16 + gl * 4;
#pragma unroll
        for (int n = 0; n < 4; ++n) {
            int col = n0 + wc * 64 + n * 16 + li;
            float bv = hasBias ? bias[col] : 0.0f;
#pragma unroll
            for (int rr = 0; rr < 4; ++rr) {
                float o = acc[m][n][rr] + bv;
                if (OUTBF16)
                    ((ushort*)Cout)[(size_t)(row + rr) * N + col] = bf16_bits(o);
                else
                    ((float*)Cout)[(size_t)(row + rr) * N + col] = o;
            }
        }
    }
}

// ---------------- fused LayerNorm(+RoPE) for q,k,v; bf16 in, bf16 out ----------------
// wave-rows: [0,32768) q; [32768,36864) k; [36864,40960) v
__global__ void ln_all(const ushort* __restrict__ qkv,
                       ushort* __restrict__ qbh, ushort* __restrict__ kbh,
                       ushort* __restrict__ vbh,
                       const float* __restrict__ qn_w, const float* __restrict__ qn_b,
                       const float* __restrict__ kn_w, const float* __restrict__ kn_b,
                       const float* __restrict__ vn_w, const float* __restrict__ vn_b) {
    int wid = blockIdx.x * 4 + (threadIdx.x >> 6);
    int lane = threadIdx.x & 63;

    if (wid < ROWS * HQ + ROWS) {  // D=128 with RoPE (q or k)
        const ushort* src;
        ushort* dst;
        const float* w;
        const float* b;
        int s;
        if (wid < ROWS * HQ) {
            int row = wid >> 3, h = wid & 7;
            src = qkv + (size_t)row * NQKV + h * DQK;
            dst = qbh + (size_t)wid * DQK;
            w = qn_w; b = qn_b;
            s = row % Ss;
        } else {
            int idx = wid - ROWS * HQ;
            src = qkv + (size_t)idx * NQKV + 1024;
            dst = kbh + (size_t)idx * DQK;
            w = kn_w; b = kn_b;
            s = idx % Ss;
        }
        ushort2 e2 = *(const ushort2*)&src[2 * lane];
        float e0 = bfu(e2.x), e1 = bfu(e2.y);
        float mu = wave_sum(e0 + e1) * (1.0f / DQK);
        float d0 = e0 - mu, d1 = e1 - mu;
        float var = wave_sum(d0 * d0 + d1 * d1) * (1.0f / DQK);
        float rs = rsqrtf(var + EPSf);
        float n0 = d0 * rs * w[2 * lane] + b[2 * lane];
        float n1 = d1 * rs * w[2 * lane + 1] + b[2 * lane + 1];
        float geom = expf((float)lane * (logf(8129.0f) / 63.0f));
        float invf = 1.0f / ((float)lane + geom);
        float th = (float)s * invf;
        float ct = cosf(th), st = sinf(th);
        float r0 = n0 * ct - n1 * st;
        float r1 = n1 * ct + n0 * st;
        ushort2 o = {bf16_bits(r0), bf16_bits(r1)};
        *(ushort2*)&dst[2 * lane] = o;
    } else {  // D=192, no rope (v)
        int idx = wid - ROWS * HQ - ROWS;
        const ushort* src = qkv + (size_t)idx * NQKV + 1152;
        ushort* dst = vbh + (size_t)idx * DV;
        float e0 = bfu(src[lane]), e1 = bfu(src[lane + 64]), e2 = bfu(src[lane + 128]);
        float mu = wave_sum(e0 + e1 + e2) * (1.0f / DV);
        float d0 = e0 - mu, d1 = e1 - mu, d2 = e2 - mu;
        float var = wave_sum(d0 * d0 + d1 * d1 + d2 * d2) * (1.0f / DV);
        float rs = rsqrtf(var + EPSf);
        dst[lane]       = bf16_bits(d0 * rs * vn_w[lane] + vn_b[lane]);
        dst[lane + 64]  = bf16_bits(d1 * rs * vn_w[lane + 64] + vn_b[lane + 64]);
        dst[lane + 128] = bf16_bits(d2 * rs * vn_w[lane + 128] + vn_b[lane + 128]);
    }
}

// ---------------- V transpose: vbh[b][t][d] -> vT[b][d][t] (bf16) ----------------
__global__ __launch_bounds__(256) void transpose_v(const ushort* __restrict__ vbh,
                                                   ushort* __restrict__ vT) {
    __shared__ ushort tb[64][72];
    int t0 = blockIdx.x * 64, d0 = blockIdx.y * 64, b = blockIdx.z;
    int tid = threadIdx.x;
#pragma unroll
    for (int i = 0; i < 2; ++i) {
        int ci = tid + i * 256;
        int t = ci >> 3, dc = ci & 7;
        short8 v = *(const short8*)&vbh[((size_t)(b * Ss + t0 + t)) * DV + d0 + dc * 8];
        *(short8*)&tb[t][dc * 8] = v;
    }
    __syncthreads();
#pragma unroll
    for (int i = 0; i < 2; ++i) {
        int ci = tid + i * 256;
        int d = ci >> 3, tc = ci & 7;
        short8 v;
#pragma unroll
        for (int j = 0; j < 8; ++j) v[j] = (short)tb[tc * 8 + j][d];
        *(short8*)&vT[((size_t)(b * DV + d0 + d)) * Ss + t0 + tc * 8] = v;
    }
}

// ---------------- MFMA flash attention with register-prefetch staging ----------------
__global__ __launch_bounds__(256, 3) void attn_mfma(const ushort* __restrict__ qbh,
                                                    const ushort* __restrict__ kbh,
                                                    const ushort* __restrict__ vT,
                                                    ushort* __restrict__ yab) {
    __shared__ ushort Klds[64 * 128];
    __shared__ ushort VTlds[192 * 64];
    __shared__ ushort Plds[4 * 16 * 64];
    int tid = threadIdx.x;
    int b = blockIdx.z, gq = blockIdx.y;
    int q0 = blockIdx.x * 64;
    int w = tid >> 6, lane = tid & 63;
    int g = lane >> 4, li = lane & 15;
    int mask = (li & 7) << 4;

    short8 qf[4];
    {
        int qrow = q0 + w * 16 + li;
        const ushort* qptr = qbh + ((size_t)(b * Ss + qrow) * HQ + gq) * DQK + g * 8;
#pragma unroll
        for (int c = 0; c < 4; ++c) qf[c] = *(const short8*)(qptr + c * 32);
    }

    // staging geometry (fixed per thread)
    int krow0 = tid >> 4, kcb = tid & 15;      // K: 4 chunks, row = krow0 + i*16
    int vrow0 = tid >> 3, vcb = tid & 7;       // V: 6 chunks, row = vrow0 + i*32
    const ushort* kbase = kbh + (size_t)b * Ss * DQK;
    const ushort* vbase = vT + (size_t)b * DV * Ss;

    short8 kreg[4], vreg[6];
    // preload tile 0
#pragma unroll
    for (int i = 0; i < 4; ++i)
        kreg[i] = *(const short8*)&kbase[(size_t)(krow0 + i * 16) * DQK + kcb * 8];
#pragma unroll
    for (int i = 0; i < 6; ++i)
        vreg[i] = *(const short8*)&vbase[(size_t)(vrow0 + i * 32) * Ss + vcb * 8];

    f32x4 pv[12];
#pragma unroll
    for (int n = 0; n < 12; ++n) pv[n] = (f32x4){0.f, 0.f, 0.f, 0.f};
    float lacc[4] = {0.f, 0.f, 0.f, 0.f};

    const float scl = 0.088388347648318447f;

    for (int kt = 0; kt < Ss / 64; ++kt) {
        // write staged registers to LDS (tile kt)
#pragma unroll
        for (int i = 0; i < 4; ++i) {
            int row = krow0 + i * 16;
            *(short8*)((char*)Klds + ((row * 256 + kcb * 16) ^ ((row & 7) << 4))) = kreg[i];
        }
#pragma unroll
        for (int i = 0; i < 6; ++i) {
            int row = vrow0 + i * 32;
            *(short8*)((char*)VTlds + ((row * 128 + vcb * 16) ^ ((row & 7) << 4))) = vreg[i];
        }
        __syncthreads();

        // prefetch tile kt+1 into registers (hides under compute below)
        if (kt + 1 < Ss / 64) {
            int t1 = (kt + 1) * 64;
#pragma unroll
            for (int i = 0; i < 4; ++i)
                kreg[i] = *(const short8*)&kbase[(size_t)(t1 + krow0 + i * 16) * DQK + kcb * 8];
#pragma unroll
            for (int i = 0; i < 6; ++i)
                vreg[i] = *(const short8*)&vbase[(size_t)(vrow0 + i * 32) * Ss + t1 + vcb * 8];
        }

        // QK^T
        f32x4 s[4];
#pragma unroll
        for (int n = 0; n < 4; ++n) s[n] = (f32x4){0.f, 0.f, 0.f, 0.f};
#pragma unroll
        for (int c = 0; c < 4; ++c) {
#pragma unroll
            for (int n = 0; n < 4; ++n) {
                short8 kf = *(const short8*)((char*)Klds +
                            ((li * 256 + g * 16 + n * 4096 + c * 64) ^ mask));
                s[n] = __builtin_amdgcn_mfma_f32_16x16x32_bf16(qf[c], kf, s[n], 0, 0, 0);
            }
        }

        // P = exp(5*tanh(z/5)); bounded logits -> fixed-shift softmax
        float rsum[4] = {0.f, 0.f, 0.f, 0.f};
#pragma unroll
        for (int n = 0; n < 4; ++n) {
#pragma unroll
            for (int rr = 0; rr < 4; ++rr) {
                float z = s[n][rr] * scl;
                float u = __expf(0.4f * z);
                float p = __expf(5.0f - 10.0f * __builtin_amdgcn_rcpf(u + 1.0f));
                rsum[rr] += p;
                int row = g * 4 + rr;
                *(ushort*)((char*)Plds + w * 2048 +
                           ((row * 128 + n * 32 + li * 2) ^ ((row & 7) << 4))) = bf16_bits(p);
            }
        }
#pragma unroll
        for (int rr = 0; rr < 4; ++rr) {
            float v = rsum[rr];
            v += __shfl_xor(v, 1); v += __shfl_xor(v, 2);
            v += __shfl_xor(v, 4); v += __shfl_xor(v, 8);
            lacc[rr] += v;
        }

        // PV
#pragma unroll
        for (int c2 = 0; c2 < 2; ++c2) {
            short8 pa = *(const short8*)((char*)Plds + w * 2048 +
                        ((li * 128 + c2 * 64 + g * 16) ^ mask));
#pragma unroll
            for (int n = 0; n < 12; ++n) {
                short8 vf = *(const short8*)((char*)VTlds +
                            ((n * 2048 + li * 128 + c2 * 64 + g * 16) ^ mask));
                pv[n] = __builtin_amdgcn_mfma_f32_16x16x32_bf16(pa, vf, pv[n], 0, 0, 0);
            }
        }
        __syncthreads();
    }

    float invl[4];
#pragma unroll
    for (int rr = 0; rr < 4; ++rr) invl[rr] = 1.0f / lacc[rr];
#pragma unroll
    for (int n = 0; n < 12; ++n) {
#pragma unroll
        for (int rr = 0; rr < 4; ++rr) {
            int qr = q0 + w * 16 + g * 4 + rr;
            yab[((size_t)(b * Ss + qr) * HQ + gq) * DV + n * 16 + li] =
                bf16_bits(pv[n][rr] * invl[rr]);
        }
    }
}

// ---------------- launch ----------------
extern "C" void kernel_launch(void* const* d_in, const int* in_sizes, int n_in,
                              void* d_out, int out_size, void* d_ws, size_t ws_size,
                              hipStream_t stream) {
    const float* x         = (const float*)d_in[0];
    const float* bn1_scale = (const float*)d_in[1];
    const float* q_w       = (const float*)d_in[2];
    const float* k_w       = (const float*)d_in[3];
    const float* v_w       = (const float*)d_in[4];
    const float* qn_w      = (const float*)d_in[5];
    const float* qn_b      = (const float*)d_in[6];
    const float* kn_w      = (const float*)d_in[7];
    const float* kn_b      = (const float*)d_in[8];
    const float* vn_w      = (const float*)d_in[9];
    const float* vn_b      = (const float*)d_in[10];
    const float* bn2_scale = (const float*)d_in[11];
    const float* out_w     = (const float*)d_in[12];
    const float* out_b     = (const float*)d_in[13];
    float* out = (float*)d_out;

    char* wsb = (char*)d_ws;
    float* ms1 = (float*)wsb;                  // 1536 f32
    float* ms2 = ms1 + Cc;                     // 1536 f32
    char* base = wsb + 16384;
    ushort* xbh   = (ushort*)base;                              // 4096*1536 bf16 (12.6MB)
    ushort* qkvwh = xbh + (size_t)ROWS * Cc;                    // 1408*1536 bf16 (4.3MB)
    ushort* qkvbh = qkvwh + (size_t)NQKV * Cc;                  // 4096*1408 bf16 (11.5MB)
    ushort* owh   = qkvbh + (size_t)ROWS * NQKV;                // 1536*1536 bf16 (4.7MB)
    ushort* qbh   = owh + (size_t)Cc * Cc;                      // 4096*1024 bf16
    ushort* kbh   = qbh + (size_t)ROWS * HQ * DQK;              // 4096*128
    ushort* vbh   = kbh + (size_t)ROWS * DQK;                   // 4096*192
    ushort* vTb   = vbh + (size_t)ROWS * DV;                    // 2*192*2048
    ushort* yab   = vTb + (size_t)Bb * DV * Ss;                 // 4096*1536 bf16
    float*  proj  = (float*)base;  // 25MB, aliases xbh/qkvwh/qkvbh (dead by out-proj)

    hipMemsetAsync(ms1, 0, 2 * Cc * sizeof(float), stream);

    // rms_bn1 -> bf16 activations
    sq_reduce<<<dim3(Cc / 256, ROWS / 128), 256, 0, stream>>>(x, ms1, Cc);
    rms_apply_v<1><<<2048, 256, 0, stream>>>(x, ms1, bn1_scale, xbh, Cc / 4,
                                             (size_t)ROWS * Cc / 4);

    // all weights -> bf16 in one launch
    {
        int total4 = (1024 * Cc + 128 * Cc + 192 * Cc + Cc * Cc) / 4;
        cvt_all<<<(total4 + 255) / 256, 256, 0, stream>>>(q_w, k_w, v_w, out_w, qkvwh, owh);
    }

    // fused QKV projection (bf16 MFMA -> bf16)
    gemm_bf16<1><<<dim3(NQKV / 128, ROWS / 128), 256, 0, stream>>>(
        xbh, qkvwh, nullptr, qkvbh, NQKV, Cc, 0);

    // fused LayerNorm + RoPE (q,k,v) -> bf16
    ln_all<<<(ROWS * HQ + ROWS + ROWS) / 4, 256, 0, stream>>>(
        qkvbh, qbh, kbh, vbh, qn_w, qn_b, kn_w, kn_b, vn_w, vn_b);

    // V transpose
    transpose_v<<<dim3(Ss / 64, DV / 64, Bb), 256, 0, stream>>>(vbh, vTb);

    // attention -> bf16 y
    attn_mfma<<<dim3(Ss / 64, HQ, Bb), 256, 0, stream>>>(qbh, kbh, vTb, yab);

    // output projection + bias (bf16 MFMA -> f32)
    gemm_bf16<0><<<dim3(Cc / 128, ROWS / 128), 256, 0, stream>>>(
        yab, owh, out_b, proj, Cc, Cc, 1);

    // rms_bn2 -> f32 out
    sq_reduce<<<dim3(Cc / 256, ROWS / 128), 256, 0, stream>>>(proj, ms2, Cc);
    rms_apply_v<0><<<2048, 256, 0, stream>>>(proj, ms2, bn2_scale, out, Cc / 4,
                                             (size_t)ROWS * Cc / 4);
}

// Round 15
// 360.694 us; speedup vs baseline: 1.2656x; 1.2656x over previous
//
#include <hip/hip_runtime.h>
#include <hip/hip_bf16.h>
#include <math.h>

#define Bb 2
#define Ss 2048
#define Cc 1536
#define HQ 8
#define DQK 128
#define DV 192
#define ROWS (Bb*Ss)          // 4096
#define NQKV 1408             // 1024 q + 128 k + 192 v + 64 pad (11*128)
#define EPSf 1e-5f
#define CLIPf 5.0f

typedef short short8 __attribute__((ext_vector_type(8)));
typedef float f32x4 __attribute__((ext_vector_type(4)));
typedef unsigned short ushort;
typedef ushort us4 __attribute__((ext_vector_type(4)));

// ---------------- helpers ----------------
__device__ __forceinline__ float wave_sum(float v) {
#pragma unroll
    for (int off = 32; off >= 1; off >>= 1) v += __shfl_xor(v, off);
    return v;
}

__device__ __forceinline__ ushort bf16_bits(float f) {
    __hip_bfloat16 hb = __float2bfloat16(f);
    return *reinterpret_cast<ushort*>(&hb);
}

__device__ __forceinline__ float bfu(ushort u) {
    unsigned v = (unsigned)u << 16;
    return *reinterpret_cast<float*>(&v);
}

__device__ __forceinline__ void gld16(const void* g, void* l) {
    __builtin_amdgcn_global_load_lds(
        (const __attribute__((address_space(1))) void*)g,
        (__attribute__((address_space(3))) void*)l, 16, 0, 0);
}

// ---------------- rms_bn reduce (per-channel over B*S) ----------------
__global__ void sq_reduce(const float* __restrict__ x, float* __restrict__ ms, int ncols) {
    int ch = blockIdx.x * blockDim.x + threadIdx.x;
    int r0 = blockIdx.y * 128;
    float acc = 0.f;
    for (int r = r0; r < r0 + 128; ++r) {
        float v = x[(size_t)r * ncols + ch];
        acc += v * v;
    }
    atomicAdd(&ms[ch], acc);
}

// ---------------- rms apply, vectorized x4; BF16 template selects output ----------------
template <int BF16>
__global__ void rms_apply_v(const float* __restrict__ x, const float* __restrict__ ms,
                            const float* __restrict__ scale, void* __restrict__ outp,
                            int ncols4, size_t total4) {
    for (size_t i = (size_t)blockIdx.x * blockDim.x + threadIdx.x; i < total4;
         i += (size_t)gridDim.x * blockDim.x) {
        int c4 = (int)(i % ncols4);
        float4 v = ((const float4*)x)[i];
        float4 m4 = ((const float4*)ms)[c4];
        float4 s4 = ((const float4*)scale)[c4];
        float o0 = v.x * rsqrtf(m4.x * (1.0f / ROWS) + EPSf) * s4.x;
        float o1 = v.y * rsqrtf(m4.y * (1.0f / ROWS) + EPSf) * s4.y;
        float o2 = v.z * rsqrtf(m4.z * (1.0f / ROWS) + EPSf) * s4.z;
        float o3 = v.w * rsqrtf(m4.w * (1.0f / ROWS) + EPSf) * s4.w;
        if (BF16) {
            us4 o = {bf16_bits(o0), bf16_bits(o1), bf16_bits(o2), bf16_bits(o3)};
            ((us4*)outp)[i] = o;
        } else {
            float4 o = {o0, o1, o2, o3};
            ((float4*)outp)[i] = o;
        }
    }
}

// ---------------- fused fp32 -> bf16 weight conversion (4 segments) ----------------
__global__ void cvt_all(const float* __restrict__ q_w, const float* __restrict__ k_w,
                        const float* __restrict__ v_w, const float* __restrict__ ow,
                        ushort* __restrict__ qkvwh, ushort* __restrict__ owh) {
    const int QN = 1024 * Cc / 4, KN = 128 * Cc / 4, VN = 192 * Cc / 4, ON = Cc * Cc / 4;
    int i = blockIdx.x * 256 + threadIdx.x;
    const float* src;
    us4* dst;
    int off;
    if (i < QN)                  { src = q_w; dst = (us4*)qkvwh;                         off = i; }
    else if (i < QN + KN)        { src = k_w; dst = (us4*)(qkvwh + (size_t)1024 * Cc);   off = i - QN; }
    else if (i < QN + KN + VN)   { src = v_w; dst = (us4*)(qkvwh + (size_t)1152 * Cc);   off = i - QN - KN; }
    else if (i < QN + KN + VN + ON) { src = ow; dst = (us4*)owh;                         off = i - QN - KN - VN; }
    else return;
    float4 v = ((const float4*)src)[off];
    us4 o = {bf16_bits(v.x), bf16_bits(v.y), bf16_bits(v.z), bf16_bits(v.w)};
    dst[off] = o;
}

// ---------------- bf16 MFMA GEMM: C[M,N] = A[M,K] * W[N,K]^T (+bias) ----------------
// BM=BN=128, BK=32, 256 thr (2x2 waves, 64x64/wave, 4x4 frags of 16x16x32).
// OUTBF16 selects fp32 or bf16 output.
template <int OUTBF16>
__global__ __launch_bounds__(256) void gemm_bf16(const ushort* __restrict__ A,
                                                 const ushort* __restrict__ W,
                                                 const float* __restrict__ bias,
                                                 void* __restrict__ Cout,
                                                 int N, int K, int hasBias) {
    __shared__ ushort AS[4096];  // 8 KB
    __shared__ ushort WS[4096];  // 8 KB
    int tid = threadIdx.x;
    int w = tid >> 6, lane = tid & 63;
    int gl = lane >> 4, li = lane & 15;
    int wr = w >> 1, wc = w & 1;
    int m0 = blockIdx.y * 128, n0 = blockIdx.x * 128;

    int r = tid & 127, gg = tid >> 7;
    const ushort* pA = A + (size_t)(m0 + r) * K + gg * 8;
    const ushort* pW = W + (size_t)(n0 + r) * K + gg * 8;
    ushort* lA0 = &AS[w * 512];
    ushort* lA1 = &AS[2048 + w * 512];
    ushort* lW0 = &WS[w * 512];
    ushort* lW1 = &WS[2048 + w * 512];

    const ushort* fA = &AS[(gl * 128 + wr * 64 + li) * 8];
    const ushort* fW = &WS[(gl * 128 + wc * 64 + li) * 8];

    f32x4 acc[4][4];
#pragma unroll
    for (int m = 0; m < 4; ++m)
#pragma unroll
        for (int n = 0; n < 4; ++n) acc[m][n] = (f32x4){0.f, 0.f, 0.f, 0.f};

    for (int kk = 0; kk < K; kk += 32) {
        __syncthreads();
        gld16(pA + kk, lA0);
        gld16(pA + kk + 16, lA1);
        gld16(pW + kk, lW0);
        gld16(pW + kk + 16, lW1);
        __syncthreads();
        short8 a[4], b[4];
#pragma unroll
        for (int m = 0; m < 4; ++m) a[m] = *(const short8*)(fA + m * 128);
#pragma unroll
        for (int n = 0; n < 4; ++n) b[n] = *(const short8*)(fW + n * 128);
#pragma unroll
        for (int m = 0; m < 4; ++m)
#pragma unroll
            for (int n = 0; n < 4; ++n)
                acc[m][n] = __builtin_amdgcn_mfma_f32_16x16x32_bf16(a[m], b[n], acc[m][n], 0, 0, 0);
    }

#pragma unroll
    for (int m = 0; m < 4; ++m) {
        int row = m0 + wr * 64 + m * 16 + gl * 4;
#pragma unroll
        for (int n = 0; n < 4; ++n) {
            int col = n0 + wc * 64 + n * 16 + li;
            float bv = hasBias ? bias[col] : 0.0f;
#pragma unroll
            for (int rr = 0; rr < 4; ++rr) {
                float o = acc[m][n][rr] + bv;
                if (OUTBF16)
                    ((ushort*)Cout)[(size_t)(row + rr) * N + col] = bf16_bits(o);
                else
                    ((float*)Cout)[(size_t)(row + rr) * N + col] = o;
            }
        }
    }
}

// ---------------- fused LayerNorm(+RoPE) for q,k,v; bf16 in, bf16 out ----------------
// wave-rows: [0,32768) q; [32768,36864) k; [36864,40960) v
__global__ void ln_all(const ushort* __restrict__ qkv,
                       ushort* __restrict__ qbh, ushort* __restrict__ kbh,
                       ushort* __restrict__ vbh,
                       const float* __restrict__ qn_w, const float* __restrict__ qn_b,
                       const float* __restrict__ kn_w, const float* __restrict__ kn_b,
                       const float* __restrict__ vn_w, const float* __restrict__ vn_b) {
    int wid = blockIdx.x * 4 + (threadIdx.x >> 6);
    int lane = threadIdx.x & 63;

    if (wid < ROWS * HQ + ROWS) {  // D=128 with RoPE (q or k)
        const ushort* src;
        ushort* dst;
        const float* w;
        const float* b;
        int s;
        if (wid < ROWS * HQ) {
            int row = wid >> 3, h = wid & 7;
            src = qkv + (size_t)row * NQKV + h * DQK;
            dst = qbh + (size_t)wid * DQK;
            w = qn_w; b = qn_b;
            s = row % Ss;
        } else {
            int idx = wid - ROWS * HQ;
            src = qkv + (size_t)idx * NQKV + 1024;
            dst = kbh + (size_t)idx * DQK;
            w = kn_w; b = kn_b;
            s = idx % Ss;
        }
        ushort2 e2 = *(const ushort2*)&src[2 * lane];
        float e0 = bfu(e2.x), e1 = bfu(e2.y);
        float mu = wave_sum(e0 + e1) * (1.0f / DQK);
        float d0 = e0 - mu, d1 = e1 - mu;
        float var = wave_sum(d0 * d0 + d1 * d1) * (1.0f / DQK);
        float rs = rsqrtf(var + EPSf);
        float n0 = d0 * rs * w[2 * lane] + b[2 * lane];
        float n1 = d1 * rs * w[2 * lane + 1] + b[2 * lane + 1];
        float geom = expf((float)lane * (logf(8129.0f) / 63.0f));
        float invf = 1.0f / ((float)lane + geom);
        float th = (float)s * invf;
        float ct = cosf(th), st = sinf(th);
        float r0 = n0 * ct - n1 * st;
        float r1 = n1 * ct + n0 * st;
        ushort2 o = {bf16_bits(r0), bf16_bits(r1)};
        *(ushort2*)&dst[2 * lane] = o;
    } else {  // D=192, no rope (v)
        int idx = wid - ROWS * HQ - ROWS;
        const ushort* src = qkv + (size_t)idx * NQKV + 1152;
        ushort* dst = vbh + (size_t)idx * DV;
        float e0 = bfu(src[lane]), e1 = bfu(src[lane + 64]), e2 = bfu(src[lane + 128]);
        float mu = wave_sum(e0 + e1 + e2) * (1.0f / DV);
        float d0 = e0 - mu, d1 = e1 - mu, d2 = e2 - mu;
        float var = wave_sum(d0 * d0 + d1 * d1 + d2 * d2) * (1.0f / DV);
        float rs = rsqrtf(var + EPSf);
        dst[lane]       = bf16_bits(d0 * rs * vn_w[lane] + vn_b[lane]);
        dst[lane + 64]  = bf16_bits(d1 * rs * vn_w[lane + 64] + vn_b[lane + 64]);
        dst[lane + 128] = bf16_bits(d2 * rs * vn_w[lane + 128] + vn_b[lane + 128]);
    }
}

// ---------------- V transpose: vbh[b][t][d] -> vT[b][d][t] (bf16) ----------------
__global__ __launch_bounds__(256) void transpose_v(const ushort* __restrict__ vbh,
                                                   ushort* __restrict__ vT) {
    __shared__ ushort tb[64][72];
    int t0 = blockIdx.x * 64, d0 = blockIdx.y * 64, b = blockIdx.z;
    int tid = threadIdx.x;
#pragma unroll
    for (int i = 0; i < 2; ++i) {
        int ci = tid + i * 256;
        int t = ci >> 3, dc = ci & 7;
        short8 v = *(const short8*)&vbh[((size_t)(b * Ss + t0 + t)) * DV + d0 + dc * 8];
        *(short8*)&tb[t][dc * 8] = v;
    }
    __syncthreads();
#pragma unroll
    for (int i = 0; i < 2; ++i) {
        int ci = tid + i * 256;
        int d = ci >> 3, tc = ci & 7;
        short8 v;
#pragma unroll
        for (int j = 0; j < 8; ++j) v[j] = (short)tb[tc * 8 + j][d];
        *(short8*)&vT[((size_t)(b * DV + d0 + d)) * Ss + t0 + tc * 8] = v;
    }
}

// ---------------- MFMA flash attention (round-12 staging: global -> LDS direct) ----------------
__global__ __launch_bounds__(256, 2) void attn_mfma(const ushort* __restrict__ qbh,
                                                    const ushort* __restrict__ kbh,
                                                    const ushort* __restrict__ vT,
                                                    ushort* __restrict__ yab) {
    __shared__ ushort Klds[64 * 128];
    __shared__ ushort VTlds[192 * 64];
    __shared__ ushort Plds[4 * 16 * 64];
    int tid = threadIdx.x;
    int b = blockIdx.z, gq = blockIdx.y;
    int q0 = blockIdx.x * 64;
    int w = tid >> 6, lane = tid & 63;
    int g = lane >> 4, li = lane & 15;
    int mask = (li & 7) << 4;

    short8 qf[4];
    {
        int qrow = q0 + w * 16 + li;
        const ushort* qptr = qbh + ((size_t)(b * Ss + qrow) * HQ + gq) * DQK + g * 8;
#pragma unroll
        for (int c = 0; c < 4; ++c) qf[c] = *(const short8*)(qptr + c * 32);
    }

    f32x4 pv[12];
#pragma unroll
    for (int n = 0; n < 12; ++n) pv[n] = (f32x4){0.f, 0.f, 0.f, 0.f};
    float lacc[4] = {0.f, 0.f, 0.f, 0.f};

    const float scl = 0.088388347648318447f;

    for (int kt = 0; kt < Ss / 64; ++kt) {
        int t0 = kt * 64;
#pragma unroll
        for (int i = 0; i < 4; ++i) {
            int ci = tid + i * 256;
            int row = ci >> 4, cb = ci & 15;
            short8 v = *(const short8*)&kbh[(size_t)(b * Ss + t0 + row) * DQK + cb * 8];
            *(short8*)((char*)Klds + ((row * 256 + cb * 16) ^ ((row & 7) << 4))) = v;
        }
#pragma unroll
        for (int i = 0; i < 6; ++i) {
            int ci = tid + i * 256;
            int row = ci >> 3, cb = ci & 7;
            short8 v = *(const short8*)&vT[((size_t)(b * DV + row)) * Ss + t0 + cb * 8];
            *(short8*)((char*)VTlds + ((row * 128 + cb * 16) ^ ((row & 7) << 4))) = v;
        }
        __syncthreads();

        f32x4 s[4];
#pragma unroll
        for (int n = 0; n < 4; ++n) s[n] = (f32x4){0.f, 0.f, 0.f, 0.f};
#pragma unroll
        for (int c = 0; c < 4; ++c) {
#pragma unroll
            for (int n = 0; n < 4; ++n) {
                short8 kf = *(const short8*)((char*)Klds +
                            ((li * 256 + g * 16 + n * 4096 + c * 64) ^ mask));
                s[n] = __builtin_amdgcn_mfma_f32_16x16x32_bf16(qf[c], kf, s[n], 0, 0, 0);
            }
        }

        float rsum[4] = {0.f, 0.f, 0.f, 0.f};
#pragma unroll
        for (int n = 0; n < 4; ++n) {
#pragma unroll
            for (int rr = 0; rr < 4; ++rr) {
                float z = s[n][rr] * scl;
                float u = __expf(0.4f * z);
                float p = __expf(5.0f - 10.0f * __builtin_amdgcn_rcpf(u + 1.0f));
                rsum[rr] += p;
                int row = g * 4 + rr;
                *(ushort*)((char*)Plds + w * 2048 +
                           ((row * 128 + n * 32 + li * 2) ^ ((row & 7) << 4))) = bf16_bits(p);
            }
        }
#pragma unroll
        for (int rr = 0; rr < 4; ++rr) {
            float v = rsum[rr];
            v += __shfl_xor(v, 1); v += __shfl_xor(v, 2);
            v += __shfl_xor(v, 4); v += __shfl_xor(v, 8);
            lacc[rr] += v;
        }

#pragma unroll
        for (int c2 = 0; c2 < 2; ++c2) {
            short8 pa = *(const short8*)((char*)Plds + w * 2048 +
                        ((li * 128 + c2 * 64 + g * 16) ^ mask));
#pragma unroll
            for (int n = 0; n < 12; ++n) {
                short8 vf = *(const short8*)((char*)VTlds +
                            ((n * 2048 + li * 128 + c2 * 64 + g * 16) ^ mask));
                pv[n] = __builtin_amdgcn_mfma_f32_16x16x32_bf16(pa, vf, pv[n], 0, 0, 0);
            }
        }
        __syncthreads();
    }

    float invl[4];
#pragma unroll
    for (int rr = 0; rr < 4; ++rr) invl[rr] = 1.0f / lacc[rr];
#pragma unroll
    for (int n = 0; n < 12; ++n) {
#pragma unroll
        for (int rr = 0; rr < 4; ++rr) {
            int qr = q0 + w * 16 + g * 4 + rr;
            yab[((size_t)(b * Ss + qr) * HQ + gq) * DV + n * 16 + li] =
                bf16_bits(pv[n][rr] * invl[rr]);
        }
    }
}

// ---------------- launch ----------------
extern "C" void kernel_launch(void* const* d_in, const int* in_sizes, int n_in,
                              void* d_out, int out_size, void* d_ws, size_t ws_size,
                              hipStream_t stream) {
    const float* x         = (const float*)d_in[0];
    const float* bn1_scale = (const float*)d_in[1];
    const float* q_w       = (const float*)d_in[2];
    const float* k_w       = (const float*)d_in[3];
    const float* v_w       = (const float*)d_in[4];
    const float* qn_w      = (const float*)d_in[5];
    const float* qn_b      = (const float*)d_in[6];
    const float* kn_w      = (const float*)d_in[7];
    const float* kn_b      = (const float*)d_in[8];
    const float* vn_w      = (const float*)d_in[9];
    const float* vn_b      = (const float*)d_in[10];
    const float* bn2_scale = (const float*)d_in[11];
    const float* out_w     = (const float*)d_in[12];
    const float* out_b     = (const float*)d_in[13];
    float* out = (float*)d_out;

    char* wsb = (char*)d_ws;
    float* ms1 = (float*)wsb;                  // 1536 f32
    float* ms2 = ms1 + Cc;                     // 1536 f32
    char* base = wsb + 16384;
    ushort* xbh   = (ushort*)base;                              // 4096*1536 bf16 (12.6MB)
    ushort* qkvwh = xbh + (size_t)ROWS * Cc;                    // 1408*1536 bf16 (4.3MB)
    ushort* qkvbh = qkvwh + (size_t)NQKV * Cc;                  // 4096*1408 bf16 (11.5MB)
    ushort* owh   = qkvbh + (size_t)ROWS * NQKV;                // 1536*1536 bf16 (4.7MB)
    ushort* qbh   = owh + (size_t)Cc * Cc;                      // 4096*1024 bf16
    ushort* kbh   = qbh + (size_t)ROWS * HQ * DQK;              // 4096*128
    ushort* vbh   = kbh + (size_t)ROWS * DQK;                   // 4096*192
    ushort* vTb   = vbh + (size_t)ROWS * DV;                    // 2*192*2048
    ushort* yab   = vTb + (size_t)Bb * DV * Ss;                 // 4096*1536 bf16
    float*  proj  = (float*)base;  // 25MB, aliases xbh/qkvwh/qkvbh (dead by out-proj)

    hipMemsetAsync(ms1, 0, 2 * Cc * sizeof(float), stream);

    // rms_bn1 -> bf16 activations
    sq_reduce<<<dim3(Cc / 256, ROWS / 128), 256, 0, stream>>>(x, ms1, Cc);
    rms_apply_v<1><<<2048, 256, 0, stream>>>(x, ms1, bn1_scale, xbh, Cc / 4,
                                             (size_t)ROWS * Cc / 4);

    // all weights -> bf16 in one launch
    {
        int total4 = (1024 * Cc + 128 * Cc + 192 * Cc + Cc * Cc) / 4;
        cvt_all<<<(total4 + 255) / 256, 256, 0, stream>>>(q_w, k_w, v_w, out_w, qkvwh, owh);
    }

    // fused QKV projection (bf16 MFMA -> bf16)
    gemm_bf16<1><<<dim3(NQKV / 128, ROWS / 128), 256, 0, stream>>>(
        xbh, qkvwh, nullptr, qkvbh, NQKV, Cc, 0);

    // fused LayerNorm + RoPE (q,k,v) -> bf16
    ln_all<<<(ROWS * HQ + ROWS + ROWS) / 4, 256, 0, stream>>>(
        qkvbh, qbh, kbh, vbh, qn_w, qn_b, kn_w, kn_b, vn_w, vn_b);

    // V transpose
    transpose_v<<<dim3(Ss / 64, DV / 64, Bb), 256, 0, stream>>>(vbh, vTb);

    // attention -> bf16 y
    attn_mfma<<<dim3(Ss / 64, HQ, Bb), 256, 0, stream>>>(qbh, kbh, vTb, yab);

    // output projection + bias (bf16 MFMA -> f32)
    gemm_bf16<0><<<dim3(Cc / 128, ROWS / 128), 256, 0, stream>>>(
        yab, owh, out_b, proj, Cc, Cc, 1);

    // rms_bn2 -> f32 out
    sq_reduce<<<dim3(Cc / 256, ROWS / 128), 256, 0, stream>>>(proj, ms2, Cc);
    rms_apply_v<0><<<2048, 256, 0, stream>>>(proj, ms2, bn2_scale, out, Cc / 4,
                                             (size_t)ROWS * Cc / 4);
}